// Round 10
// baseline (445.811 us; speedup 1.0000x reference)
//
#include <hip/hip_runtime.h>
#include <hip/hip_bf16.h>

typedef __bf16 bf16;
typedef __attribute__((ext_vector_type(8))) __bf16 bf16x8;
typedef __attribute__((ext_vector_type(4))) __bf16 bf16x4;
typedef __attribute__((ext_vector_type(4))) float f32x4;
typedef __attribute__((ext_vector_type(4))) unsigned int uint4x;

#if __has_builtin(__builtin_amdgcn_exp2f)
#define EXP2F(x) __builtin_amdgcn_exp2f(x)
#else
#define EXP2F(x) exp2f(x)
#endif

#define AS1 __attribute__((address_space(1)))
#define AS3 __attribute__((address_space(3)))

static __device__ __forceinline__ void async_ld16(const bf16* g, bf16* l) {
  __builtin_amdgcn_global_load_lds((const AS1 void*)g, (AS3 void*)l, 16, 0, 0);
}

// f32 -> bf16 with EXPLICIT round-to-nearest-even bit arithmetic (proven in
// round 4: cvt_pk-based paths failed at ~9e-3; this passes at 2.4e-3).
// Valid for positive finite inputs (exp2 output); no NaN handling needed.
static __device__ __forceinline__ unsigned bf16rne(float x) {
  unsigned u = __float_as_uint(x);
  return (u + 0x7fffu + ((u >> 16) & 1u)) >> 16;
}
static __device__ __forceinline__ unsigned pack2(float a, float b) {
  return bf16rne(a) | (bf16rne(b) << 16);
}

// ---------------- fused fp32 -> bf16 conversion (x, qkv_w, fc_w) ----------
__global__ void cvt3_kernel(const float* __restrict__ x, const float* __restrict__ qw,
                            const float* __restrict__ fw, bf16* __restrict__ xb,
                            bf16* __restrict__ qwb, bf16* __restrict__ fwb) {
  int b = blockIdx.x;
  const float* src;
  bf16* dst;
  int i;
  if (b < 4096) { src = x; dst = xb; i = b * 256 + threadIdx.x; }
  else if (b < 7168) { src = qw; dst = qwb; i = (b - 4096) * 256 + threadIdx.x; }
  else { src = fw; dst = fwb; i = (b - 7168) * 256 + threadIdx.x; }
  f32x4 v = *(const f32x4*)(src + (size_t)i * 4);
  bf16x4 o;
  o[0] = (bf16)v[0]; o[1] = (bf16)v[1]; o[2] = (bf16)v[2]; o[3] = (bf16)v[3];
  *(bf16x4*)(dst + (size_t)i * 4) = o;
}

// ---------------- BT-GEMM: C[M,N] = A[M,K] @ B[N,K]^T ----------------
// (byte-identical to the passing rounds 8/9: 2-phase double-buffer + T2
// pre-swizzled-source XOR swizzle on the fragment reads.)
// MODE 0 epilogue: bias + head_mask; Q -> [nh][s][d] (x log2(e)/8);
//   K -> fragment-major Kf with the LANE-LOCAL-P permutation baked in
//     (key g at C-tile ct = 2*(g>>5)+((g>>2)&1), row i = ((g>>3)&3)*4+(g&3));
//   V -> natural fragment-major Vf. Both key-linear at 64-key granularity.
// MODE 1: fp32 out = acc + bias.
#define GEMM_STAGE(k0_, buf_)                                                    \
  {                                                                              \
    async_ld16(A + (size_t)(rowBase + r0) * Kdim + (k0_) + csw, &As[buf_][f0]);  \
    async_ld16(A + (size_t)(rowBase + r1) * Kdim + (k0_) + csw, &As[buf_][f1]);  \
    async_ld16(Bw + (size_t)(colBase + r0) * Kdim + (k0_) + csw, &Bs[buf_][f0]); \
    async_ld16(Bw + (size_t)(colBase + r1) * Kdim + (k0_) + csw, &Bs[buf_][f1]); \
  }

template <int MODE>
__global__ __launch_bounds__(256, 2) void gemm_bt_kernel(
    const bf16* __restrict__ A, const bf16* __restrict__ Bw,
    const float* __restrict__ bias, const float* __restrict__ hm,
    bf16* __restrict__ Qp, bf16* __restrict__ Kp, bf16* __restrict__ Vp,
    float* __restrict__ outF, int Ncols, int Kdim, int rowBlkCount) {
  __shared__ bf16 As[2][128 * 32];
  __shared__ bf16 Bs[2][128 * 32];
  const int t = threadIdx.x, lane = t & 63, w = t >> 6;
  const int wr = w >> 1, wc = w & 1;
  const int j = lane & 15, quad = lane >> 4;
  const int rowBlk = blockIdx.x % rowBlkCount;
  const int colBlk = blockIdx.x / rowBlkCount;
  const int rowBase = rowBlk * 128, colBase = colBlk * 128;

  f32x4 acc[4][4];
  const f32x4 z4 = {0.f, 0.f, 0.f, 0.f};
#pragma unroll
  for (int i = 0; i < 4; ++i)
#pragma unroll
    for (int jj = 0; jj < 4; ++jj) acc[i][jj] = z4;

  const int f0 = t * 8;
  const int f1 = f0 + 2048;
  const int r0 = f0 >> 5, r1 = r0 + 64;
  const int csw = (((t & 3) ^ ((r0 >> 1) & 3))) * 8;
  const int qsw = (quad ^ ((j >> 1) & 3)) * 8;

  GEMM_STAGE(0, 0);
  int buf = 0;
  for (int k0 = 0; k0 < Kdim; k0 += 32) {
    __syncthreads();  // buf staged; all waves done reading buf^1
    if (k0 + 32 < Kdim) GEMM_STAGE(k0 + 32, buf ^ 1);  // overlaps compute below
    bf16x8 af[4], bfr[4];
#pragma unroll
    for (int i = 0; i < 4; ++i)
      af[i] = *(const bf16x8*)&As[buf][(wr * 64 + i * 16 + j) * 32 + qsw];
#pragma unroll
    for (int jj = 0; jj < 4; ++jj)
      bfr[jj] = *(const bf16x8*)&Bs[buf][(wc * 64 + jj * 16 + j) * 32 + qsw];
#pragma unroll
    for (int i = 0; i < 4; ++i)
#pragma unroll
      for (int jj = 0; jj < 4; ++jj)
        acc[i][jj] = __builtin_amdgcn_mfma_f32_16x16x32_bf16(af[i], bfr[jj], acc[i][jj], 0, 0, 0);
    buf ^= 1;
  }

  if (MODE == 0) {
#pragma unroll
    for (int jj = 0; jj < 4; ++jj) {
      int col = colBase + wc * 64 + jj * 16 + j;
      int hh = col / 192;
      int rem = col - hh * 192;
      int mm = rem >> 6;   // wave-uniform (16-col runs never cross a 64 boundary)
      int dd = rem & 63;
      float hmv = hm[hh];
      float bv = bias[col];
      float sc = (mm == 0) ? hmv * 0.18033688011112042f : hmv;  // log2(e)/8 folded into Q
#pragma unroll
      for (int i = 0; i < 4; ++i) {
#pragma unroll
        for (int r = 0; r < 4; ++r) {
          int row = rowBase + wr * 64 + i * 16 + quad * 4 + r;
          int n = row >> 11, ss = row & 2047;
          size_t nh = (size_t)(n * 16 + hh);
          float val = (acc[i][jj][r] + bv) * sc;
          if (mm == 0) {
            Qp[nh * 131072 + ss * 64 + dd] = (bf16)val;
          } else if (mm == 1) {
            // lane-local-P Kf: g = ss&127, T = ss>>7,
            // ct = 2*((g>>5)&3) + ((g>>2)&1), i = ((g>>3)&3)*4 + (g&3)
            size_t idx = nh * 131072 + (size_t)(ss >> 7) * 8192 +
                         (size_t)(2 * ((ss >> 5) & 3) + ((ss >> 2) & 1)) * 1024 +
                         (dd >> 5) * 512 + ((dd >> 3) & 3) * 128 +
                         (((ss >> 3) & 3) * 4 + (ss & 3)) * 8 + (dd & 7);
            Kp[idx] = (bf16)val;
          } else {
            // natural fragment-major V: tile (ss>>7), block (kk=(ss>>5)&3, dt=dd>>4),
            // within block quad=(ss>>3)&3, j=dd&15, elem=ss&7
            size_t idx = nh * 131072 + (size_t)(ss >> 7) * 8192 +
                         (((ss >> 5) & 3) * 4 + (dd >> 4)) * 512 +
                         ((ss >> 3) & 3) * 128 + (dd & 15) * 8 + (ss & 7);
            Vp[idx] = (bf16)val;
          }
        }
      }
    }
  } else {
#pragma unroll
    for (int jj = 0; jj < 4; ++jj) {
      int col = colBase + wc * 64 + jj * 16 + j;
      float bv = bias[col];
#pragma unroll
      for (int i = 0; i < 4; ++i)
#pragma unroll
        for (int r = 0; r < 4; ++r) {
          int row = rowBase + wr * 64 + i * 16 + quad * 4 + r;
          outF[(size_t)row * Ncols + col] = acc[i][jj][r] + bv;
        }
    }
  }
}

// ---------------- Flash attention: 8-wave block, in-block merge, V-DIRECT ---
// ROUND-10 CHANGE (one variable): V is read STRAIGHT FROM GLOBAL (L2) in the
// PV step instead of being staged through LDS. Rationale: round-9 counters
// (MfmaUtil 26 / VALU 48 / HBM 6 / occ 32) show latency-bound at 16 waves/CU,
// and the limiter is LDS capacity (66.5KB -> 2 blocks/CU), not VGPR (64).
// V is consumed in exactly its global layout (linear within each 4096-elem
// subtile), shared by 4 waves, and the whole per-block V set (128KB) is
// L2-resident (HBM 6%) -- the LDS round-trip buys nothing but occupancy loss.
// LDS 66.5 -> 33KB; __launch_bounds__(512,6) caps VGPR at 85 -> 3 blocks/CU
// = 24 waves/CU (+50%). Zero new sync semantics: V is read-only global, no
// race surface. K staging/double-buffer and ALL arithmetic byte-identical
// to round 9 (same values, same op order -> absmax identical).
#define FLASH_STAGE_K(tileIdx, KsBuf)                                       \
  {                                                                         \
    const bf16* kn_ = Kc + (tileIdx) * 4096;                                \
    _Pragma("unroll")                                                       \
    for (int p = 0; p < 2; ++p) {                                           \
      int c = (p * 256 + ts) * 8;                                           \
      async_ld16(kn_ + c, &(KsBuf)[c]);                                     \
    }                                                                       \
  }

#define FLASH_TILE(tileIdx, KsBuf)                                          \
  {                                                                         \
    unsigned pkd[2][4][2];                                                  \
    _Pragma("unroll")                                                       \
    for (int ct = 0; ct < 4; ++ct) {                                        \
      bf16x8 kf0 = *(const bf16x8*)&(KsBuf)[ct * 1024 + lane * 8];          \
      bf16x8 kf1 = *(const bf16x8*)&(KsBuf)[ct * 1024 + 512 + lane * 8];    \
      _Pragma("unroll")                                                     \
      for (int rt = 0; rt < 2; ++rt) {                                      \
        f32x4 sv = z4;                                                      \
        sv = __builtin_amdgcn_mfma_f32_16x16x32_bf16(kf0, qf[rt][0], sv, 0, 0, 0); \
        sv = __builtin_amdgcn_mfma_f32_16x16x32_bf16(kf1, qf[rt][1], sv, 0, 0, 0); \
        float p0 = EXP2F(sv[0]), p1 = EXP2F(sv[1]);                         \
        float p2 = EXP2F(sv[2]), p3 = EXP2F(sv[3]);                         \
        lrow[rt] += (p0 + p1) + (p2 + p3);                                  \
        pkd[rt][ct][0] = pack2(p0, p1);                                     \
        pkd[rt][ct][1] = pack2(p2, p3);                                     \
      }                                                                     \
    }                                                                       \
    const bf16* vt_ = Vc + (tileIdx) * 4096;                                \
    _Pragma("unroll")                                                       \
    for (int kk = 0; kk < 2; ++kk) {                                        \
      union { uint4x u; bf16x8 h; } pa[2];                                  \
      _Pragma("unroll")                                                     \
      for (int rt = 0; rt < 2; ++rt)                                        \
        pa[rt].u = (uint4x){pkd[rt][2 * kk][0], pkd[rt][2 * kk][1],         \
                            pkd[rt][2 * kk + 1][0], pkd[rt][2 * kk + 1][1]};\
      _Pragma("unroll")                                                     \
      for (int dt = 0; dt < 4; ++dt) {                                      \
        bf16x8 vf = *(const bf16x8*)&vt_[(kk * 4 + dt) * 512 + lane * 8];   \
        oacc[0][dt] = __builtin_amdgcn_mfma_f32_16x16x32_bf16(pa[0].h, vf, oacc[0][dt], 0, 0, 0); \
        oacc[1][dt] = __builtin_amdgcn_mfma_f32_16x16x32_bf16(pa[1].h, vf, oacc[1][dt], 0, 0, 0); \
      }                                                                     \
    }                                                                       \
  }

__global__ __launch_bounds__(512, 6) void flash_kernel(const bf16* __restrict__ Qp,
                                                       const bf16* __restrict__ Kf,
                                                       const bf16* __restrict__ Vf,
                                                       bf16* __restrict__ attn) {
  __shared__ bf16 Kst[2][2][4096];   // [chunk][buf][..]  32 KB (Osh overlays)
  __shared__ float Lsh[8][32];       // per-wave folded l  1 KB
  const int t = threadIdx.x, lane = t & 63, w = t >> 6;
  const int ts = t & 255;            // thread id within chunk-half
  const int hc = t >> 8;             // chunk (0: waves 0-3, 1: waves 4-7)
  const int j = lane & 15, quad = lane >> 4;
  const int b = blockIdx.x;
  const int qt = b >> 5;             // [0,16)
  const int nh = b & 31;
  const int q0 = qt * 128 + (w & 3) * 32;
  const bf16* Qb = Qp + (size_t)nh * 131072;
  const bf16* Kc = Kf + (size_t)nh * 131072 + hc * 65536;
  const bf16* Vc = Vf + (size_t)nh * 131072 + hc * 65536;

  bf16x8 qf[2][2];
#pragma unroll
  for (int rt = 0; rt < 2; ++rt)
#pragma unroll
    for (int kd = 0; kd < 2; ++kd)
      qf[rt][kd] = *(const bf16x8*)&Qb[(size_t)(q0 + rt * 16 + j) * 64 + kd * 32 + quad * 8];

  float lrow[2] = {0.f, 0.f};
  f32x4 oacc[2][4];
  const f32x4 z4 = {0.f, 0.f, 0.f, 0.f};
#pragma unroll
  for (int rt = 0; rt < 2; ++rt)
#pragma unroll
    for (int dt = 0; dt < 4; ++dt) oacc[rt][dt] = z4;

  // prologue: stage K sub-tile 0 into buffer 0
  FLASH_STAGE_K(0, Kst[hc][0]);

  for (int it2 = 0; it2 < 8; ++it2) {
    __syncthreads();  // drains buf0 staging; all waves done reading buf1
    FLASH_STAGE_K(it2 * 2 + 1, Kst[hc][1]);   // overlaps compute below
    FLASH_TILE(it2 * 2, Kst[hc][0]);
    __syncthreads();  // drains buf1 staging; all waves done reading buf0
    if (it2 < 7) FLASH_STAGE_K(it2 * 2 + 2, Kst[hc][0]);
    FLASH_TILE(it2 * 2 + 1, Kst[hc][1]);
  }

  // ---- in-block chunk merge ----
  // fold l across quads: lane (0,j) holds l for q = q0 + rt*16 + j
  float lf[2];
#pragma unroll
  for (int rt = 0; rt < 2; ++rt) {
    float l = lrow[rt];
    l += __shfl_xor(l, 16);
    l += __shfl_xor(l, 32);
    lf[rt] = l;
  }
  __syncthreads();  // all waves done with Kst -> safe to overlay Osh
  if (quad == 0) {
    Lsh[w][j] = lf[0];
    Lsh[w][16 + j] = lf[1];
  }
  float* Osh = (float*)&Kst[0][0][0];  // 32 KB = 4 waves x 2rt x 4dt x 4r x 64
  if (w >= 4) {
    int wb = w - 4;
#pragma unroll
    for (int rt = 0; rt < 2; ++rt)
#pragma unroll
      for (int dt = 0; dt < 4; ++dt)
#pragma unroll
        for (int r = 0; r < 4; ++r)
          Osh[((((wb * 2 + rt) * 4 + dt) * 4) + r) * 64 + lane] = oacc[rt][dt][r];
  }
  __syncthreads();  // Osh + Lsh visible
  if (w < 4) {
    int n = nh >> 4, h = nh & 15;
    float inv[2][4];
#pragma unroll
    for (int rt = 0; rt < 2; ++rt)
#pragma unroll
      for (int r = 0; r < 4; ++r) {
        int idx = rt * 16 + quad * 4 + r;
        inv[rt][r] = 1.0f / (Lsh[w][idx] + Lsh[w + 4][idx]);
      }
#pragma unroll
    for (int rt = 0; rt < 2; ++rt)
#pragma unroll
      for (int r = 0; r < 4; ++r) {
        int s = q0 + rt * 16 + quad * 4 + r;
        size_t base = ((size_t)(n * 2048 + s)) * 1024 + h * 64;
#pragma unroll
        for (int dt = 0; dt < 4; ++dt) {
          float o = oacc[rt][dt][r] +
                    Osh[((((w * 2 + rt) * 4 + dt) * 4) + r) * 64 + lane];
          attn[base + dt * 16 + j] = (bf16)(o * inv[rt][r]);
        }
      }
  }
}

extern "C" void kernel_launch(void* const* d_in, const int* in_sizes, int n_in,
                              void* d_out, int out_size, void* d_ws, size_t ws_size,
                              hipStream_t stream) {
  const float* x = (const float*)d_in[0];
  const float* head_mask = (const float*)d_in[1];
  const float* qkv_w = (const float*)d_in[2];
  const float* qkv_b = (const float*)d_in[3];
  const float* fc_w = (const float*)d_in[4];
  const float* fc_b = (const float*)d_in[5];
  float* out = (float*)d_out;

  char* ws = (char*)d_ws;
  bf16* x_bf    = (bf16*)(ws + 0);                    // 8 MB (later reused as attn)
  bf16* qkvw_bf = (bf16*)(ws + ((size_t)8 << 20));    // 6 MB
  bf16* fcw_bf  = (bf16*)(ws + ((size_t)14 << 20));   // 2 MB
  bf16* Qp      = (bf16*)(ws + ((size_t)16 << 20));   // 8 MB
  bf16* Kf      = (bf16*)(ws + ((size_t)24 << 20));   // 8 MB (fragment-major K, lane-local-P perm)
  bf16* Vf      = (bf16*)(ws + ((size_t)32 << 20));   // 8 MB (fragment-major V, natural order)
  bf16* attn = x_bf;              // x_bf dead after gemm1

  cvt3_kernel<<<8192, 256, 0, stream>>>(x, qkv_w, fc_w, x_bf, qkvw_bf, fcw_bf);
  gemm_bt_kernel<0><<<32 * 24, 256, 0, stream>>>(x_bf, qkvw_bf, qkv_b, head_mask,
                                                 Qp, Kf, Vf, nullptr, 3072, 1024, 32);
  flash_kernel<<<512, 512, 0, stream>>>(Qp, Kf, Vf, attn);
  gemm_bt_kernel<1><<<32 * 8, 256, 0, stream>>>(attn, fcw_bf, fc_b, nullptr,
                                                nullptr, nullptr, nullptr, out, 1024, 1024, 32);
}

// Round 11
// 200.152 us; speedup vs baseline: 2.2274x; 2.2274x over previous
//
#include <hip/hip_runtime.h>
#include <hip/hip_bf16.h>

typedef __bf16 bf16;
typedef __attribute__((ext_vector_type(8))) __bf16 bf16x8;
typedef __attribute__((ext_vector_type(4))) __bf16 bf16x4;
typedef __attribute__((ext_vector_type(4))) float f32x4;
typedef __attribute__((ext_vector_type(4))) unsigned int uint4x;

#if __has_builtin(__builtin_amdgcn_exp2f)
#define EXP2F(x) __builtin_amdgcn_exp2f(x)
#else
#define EXP2F(x) exp2f(x)
#endif

#define AS1 __attribute__((address_space(1)))
#define AS3 __attribute__((address_space(3)))

static __device__ __forceinline__ void async_ld16(const bf16* g, bf16* l) {
  __builtin_amdgcn_global_load_lds((const AS1 void*)g, (AS3 void*)l, 16, 0, 0);
}

// f32 -> bf16 with EXPLICIT round-to-nearest-even bit arithmetic (proven in
// round 4: cvt_pk-based paths failed at ~9e-3; this passes at 2.4e-3).
// Valid for positive finite inputs (exp2 output); no NaN handling needed.
static __device__ __forceinline__ unsigned bf16rne(float x) {
  unsigned u = __float_as_uint(x);
  return (u + 0x7fffu + ((u >> 16) & 1u)) >> 16;
}
static __device__ __forceinline__ unsigned pack2(float a, float b) {
  return bf16rne(a) | (bf16rne(b) << 16);
}

// ---------------- fused fp32 -> bf16 conversion (x, qkv_w, fc_w) ----------
__global__ void cvt3_kernel(const float* __restrict__ x, const float* __restrict__ qw,
                            const float* __restrict__ fw, bf16* __restrict__ xb,
                            bf16* __restrict__ qwb, bf16* __restrict__ fwb) {
  int b = blockIdx.x;
  const float* src;
  bf16* dst;
  int i;
  if (b < 4096) { src = x; dst = xb; i = b * 256 + threadIdx.x; }
  else if (b < 7168) { src = qw; dst = qwb; i = (b - 4096) * 256 + threadIdx.x; }
  else { src = fw; dst = fwb; i = (b - 7168) * 256 + threadIdx.x; }
  f32x4 v = *(const f32x4*)(src + (size_t)i * 4);
  bf16x4 o;
  o[0] = (bf16)v[0]; o[1] = (bf16)v[1]; o[2] = (bf16)v[2]; o[3] = (bf16)v[3];
  *(bf16x4*)(dst + (size_t)i * 4) = o;
}

// ---------------- BT-GEMM: C[M,N] = A[M,K] @ B[N,K]^T ----------------
// (byte-identical to the passing rounds 8/9: 2-phase double-buffer + T2
// pre-swizzled-source XOR swizzle on the fragment reads.)
// MODE 0 epilogue: bias + head_mask; Q -> [nh][s][d] (x log2(e)/8);
//   K -> fragment-major Kf with the LANE-LOCAL-P permutation baked in
//     (key g at C-tile ct = 2*(g>>5)+((g>>2)&1), row i = ((g>>3)&3)*4+(g&3));
//   V -> natural fragment-major Vf. Both key-linear at 64-key granularity.
// MODE 1: fp32 out = acc + bias.
#define GEMM_STAGE(k0_, buf_)                                                    \
  {                                                                              \
    async_ld16(A + (size_t)(rowBase + r0) * Kdim + (k0_) + csw, &As[buf_][f0]);  \
    async_ld16(A + (size_t)(rowBase + r1) * Kdim + (k0_) + csw, &As[buf_][f1]);  \
    async_ld16(Bw + (size_t)(colBase + r0) * Kdim + (k0_) + csw, &Bs[buf_][f0]); \
    async_ld16(Bw + (size_t)(colBase + r1) * Kdim + (k0_) + csw, &Bs[buf_][f1]); \
  }

template <int MODE>
__global__ __launch_bounds__(256, 2) void gemm_bt_kernel(
    const bf16* __restrict__ A, const bf16* __restrict__ Bw,
    const float* __restrict__ bias, const float* __restrict__ hm,
    bf16* __restrict__ Qp, bf16* __restrict__ Kp, bf16* __restrict__ Vp,
    float* __restrict__ outF, int Ncols, int Kdim, int rowBlkCount) {
  __shared__ bf16 As[2][128 * 32];
  __shared__ bf16 Bs[2][128 * 32];
  const int t = threadIdx.x, lane = t & 63, w = t >> 6;
  const int wr = w >> 1, wc = w & 1;
  const int j = lane & 15, quad = lane >> 4;
  const int rowBlk = blockIdx.x % rowBlkCount;
  const int colBlk = blockIdx.x / rowBlkCount;
  const int rowBase = rowBlk * 128, colBase = colBlk * 128;

  f32x4 acc[4][4];
  const f32x4 z4 = {0.f, 0.f, 0.f, 0.f};
#pragma unroll
  for (int i = 0; i < 4; ++i)
#pragma unroll
    for (int jj = 0; jj < 4; ++jj) acc[i][jj] = z4;

  const int f0 = t * 8;
  const int f1 = f0 + 2048;
  const int r0 = f0 >> 5, r1 = r0 + 64;
  const int csw = (((t & 3) ^ ((r0 >> 1) & 3))) * 8;
  const int qsw = (quad ^ ((j >> 1) & 3)) * 8;

  GEMM_STAGE(0, 0);
  int buf = 0;
  for (int k0 = 0; k0 < Kdim; k0 += 32) {
    __syncthreads();  // buf staged; all waves done reading buf^1
    if (k0 + 32 < Kdim) GEMM_STAGE(k0 + 32, buf ^ 1);  // overlaps compute below
    bf16x8 af[4], bfr[4];
#pragma unroll
    for (int i = 0; i < 4; ++i)
      af[i] = *(const bf16x8*)&As[buf][(wr * 64 + i * 16 + j) * 32 + qsw];
#pragma unroll
    for (int jj = 0; jj < 4; ++jj)
      bfr[jj] = *(const bf16x8*)&Bs[buf][(wc * 64 + jj * 16 + j) * 32 + qsw];
#pragma unroll
    for (int i = 0; i < 4; ++i)
#pragma unroll
      for (int jj = 0; jj < 4; ++jj)
        acc[i][jj] = __builtin_amdgcn_mfma_f32_16x16x32_bf16(af[i], bfr[jj], acc[i][jj], 0, 0, 0);
    buf ^= 1;
  }

  if (MODE == 0) {
#pragma unroll
    for (int jj = 0; jj < 4; ++jj) {
      int col = colBase + wc * 64 + jj * 16 + j;
      int hh = col / 192;
      int rem = col - hh * 192;
      int mm = rem >> 6;   // wave-uniform (16-col runs never cross a 64 boundary)
      int dd = rem & 63;
      float hmv = hm[hh];
      float bv = bias[col];
      float sc = (mm == 0) ? hmv * 0.18033688011112042f : hmv;  // log2(e)/8 folded into Q
#pragma unroll
      for (int i = 0; i < 4; ++i) {
#pragma unroll
        for (int r = 0; r < 4; ++r) {
          int row = rowBase + wr * 64 + i * 16 + quad * 4 + r;
          int n = row >> 11, ss = row & 2047;
          size_t nh = (size_t)(n * 16 + hh);
          float val = (acc[i][jj][r] + bv) * sc;
          if (mm == 0) {
            Qp[nh * 131072 + ss * 64 + dd] = (bf16)val;
          } else if (mm == 1) {
            // lane-local-P Kf: g = ss&127, T = ss>>7,
            // ct = 2*((g>>5)&3) + ((g>>2)&1), i = ((g>>3)&3)*4 + (g&3)
            size_t idx = nh * 131072 + (size_t)(ss >> 7) * 8192 +
                         (size_t)(2 * ((ss >> 5) & 3) + ((ss >> 2) & 1)) * 1024 +
                         (dd >> 5) * 512 + ((dd >> 3) & 3) * 128 +
                         (((ss >> 3) & 3) * 4 + (ss & 3)) * 8 + (dd & 7);
            Kp[idx] = (bf16)val;
          } else {
            // natural fragment-major V: tile (ss>>7), block (kk=(ss>>5)&3, dt=dd>>4),
            // within block quad=(ss>>3)&3, j=dd&15, elem=ss&7
            size_t idx = nh * 131072 + (size_t)(ss >> 7) * 8192 +
                         (((ss >> 5) & 3) * 4 + (dd >> 4)) * 512 +
                         ((ss >> 3) & 3) * 128 + (dd & 15) * 8 + (ss & 7);
            Vp[idx] = (bf16)val;
          }
        }
      }
    }
  } else {
#pragma unroll
    for (int jj = 0; jj < 4; ++jj) {
      int col = colBase + wc * 64 + jj * 16 + j;
      float bv = bias[col];
#pragma unroll
      for (int i = 0; i < 4; ++i)
#pragma unroll
        for (int r = 0; r < 4; ++r) {
          int row = rowBase + wr * 64 + i * 16 + quad * 4 + r;
          outF[(size_t)row * Ncols + col] = acc[i][jj][r] + bv;
        }
    }
  }
}

// ---------------- Flash attention: 8-wave block, in-block merge, V-DIRECT ---
// ROUND-11: round-10 post-mortem isolated the regression to the
// __launch_bounds__(512,6) VGPR cap (85): the compiler demoted accumulators
// to scratch (VGPR 40, 1.48 GB spill traffic, 6x slower). The V-direct idea
// itself is sound (V is L2-resident, consumed in its exact global layout,
// bit-identical bytes). KEEP V-direct, REVERT the bound to (512,4) (VGPR cap
// 128, same 2 blocks/CU as the passing round 9). Win channel is now halved
// barrier-coupled staging (each __syncthreads drains 2 async loads/thread,
// not 4) + V loads hoistable over the exp2/pack VALU phase.
// Guard: occupancy and arithmetic identical to round 9, so worst case ~= 55us.
#define FLASH_STAGE_K(tileIdx, KsBuf)                                       \
  {                                                                         \
    const bf16* kn_ = Kc + (tileIdx) * 4096;                                \
    _Pragma("unroll")                                                       \
    for (int p = 0; p < 2; ++p) {                                           \
      int c = (p * 256 + ts) * 8;                                           \
      async_ld16(kn_ + c, &(KsBuf)[c]);                                     \
    }                                                                       \
  }

#define FLASH_TILE(tileIdx, KsBuf)                                          \
  {                                                                         \
    unsigned pkd[2][4][2];                                                  \
    _Pragma("unroll")                                                       \
    for (int ct = 0; ct < 4; ++ct) {                                        \
      bf16x8 kf0 = *(const bf16x8*)&(KsBuf)[ct * 1024 + lane * 8];          \
      bf16x8 kf1 = *(const bf16x8*)&(KsBuf)[ct * 1024 + 512 + lane * 8];    \
      _Pragma("unroll")                                                     \
      for (int rt = 0; rt < 2; ++rt) {                                      \
        f32x4 sv = z4;                                                      \
        sv = __builtin_amdgcn_mfma_f32_16x16x32_bf16(kf0, qf[rt][0], sv, 0, 0, 0); \
        sv = __builtin_amdgcn_mfma_f32_16x16x32_bf16(kf1, qf[rt][1], sv, 0, 0, 0); \
        float p0 = EXP2F(sv[0]), p1 = EXP2F(sv[1]);                         \
        float p2 = EXP2F(sv[2]), p3 = EXP2F(sv[3]);                         \
        lrow[rt] += (p0 + p1) + (p2 + p3);                                  \
        pkd[rt][ct][0] = pack2(p0, p1);                                     \
        pkd[rt][ct][1] = pack2(p2, p3);                                     \
      }                                                                     \
    }                                                                       \
    const bf16* vt_ = Vc + (tileIdx) * 4096;                                \
    _Pragma("unroll")                                                       \
    for (int kk = 0; kk < 2; ++kk) {                                        \
      union { uint4x u; bf16x8 h; } pa[2];                                  \
      _Pragma("unroll")                                                     \
      for (int rt = 0; rt < 2; ++rt)                                        \
        pa[rt].u = (uint4x){pkd[rt][2 * kk][0], pkd[rt][2 * kk][1],         \
                            pkd[rt][2 * kk + 1][0], pkd[rt][2 * kk + 1][1]};\
      _Pragma("unroll")                                                     \
      for (int dt = 0; dt < 4; ++dt) {                                      \
        bf16x8 vf = *(const bf16x8*)&vt_[(kk * 4 + dt) * 512 + lane * 8];   \
        oacc[0][dt] = __builtin_amdgcn_mfma_f32_16x16x32_bf16(pa[0].h, vf, oacc[0][dt], 0, 0, 0); \
        oacc[1][dt] = __builtin_amdgcn_mfma_f32_16x16x32_bf16(pa[1].h, vf, oacc[1][dt], 0, 0, 0); \
      }                                                                     \
    }                                                                       \
  }

__global__ __launch_bounds__(512, 4) void flash_kernel(const bf16* __restrict__ Qp,
                                                       const bf16* __restrict__ Kf,
                                                       const bf16* __restrict__ Vf,
                                                       bf16* __restrict__ attn) {
  __shared__ bf16 Kst[2][2][4096];   // [chunk][buf][..]  32 KB (Osh overlays)
  __shared__ float Lsh[8][32];       // per-wave folded l  1 KB
  const int t = threadIdx.x, lane = t & 63, w = t >> 6;
  const int ts = t & 255;            // thread id within chunk-half
  const int hc = t >> 8;             // chunk (0: waves 0-3, 1: waves 4-7)
  const int j = lane & 15, quad = lane >> 4;
  const int b = blockIdx.x;
  const int qt = b >> 5;             // [0,16)
  const int nh = b & 31;
  const int q0 = qt * 128 + (w & 3) * 32;
  const bf16* Qb = Qp + (size_t)nh * 131072;
  const bf16* Kc = Kf + (size_t)nh * 131072 + hc * 65536;
  const bf16* Vc = Vf + (size_t)nh * 131072 + hc * 65536;

  bf16x8 qf[2][2];
#pragma unroll
  for (int rt = 0; rt < 2; ++rt)
#pragma unroll
    for (int kd = 0; kd < 2; ++kd)
      qf[rt][kd] = *(const bf16x8*)&Qb[(size_t)(q0 + rt * 16 + j) * 64 + kd * 32 + quad * 8];

  float lrow[2] = {0.f, 0.f};
  f32x4 oacc[2][4];
  const f32x4 z4 = {0.f, 0.f, 0.f, 0.f};
#pragma unroll
  for (int rt = 0; rt < 2; ++rt)
#pragma unroll
    for (int dt = 0; dt < 4; ++dt) oacc[rt][dt] = z4;

  // prologue: stage K sub-tile 0 into buffer 0
  FLASH_STAGE_K(0, Kst[hc][0]);

  for (int it2 = 0; it2 < 8; ++it2) {
    __syncthreads();  // drains buf0 staging; all waves done reading buf1
    FLASH_STAGE_K(it2 * 2 + 1, Kst[hc][1]);   // overlaps compute below
    FLASH_TILE(it2 * 2, Kst[hc][0]);
    __syncthreads();  // drains buf1 staging; all waves done reading buf0
    if (it2 < 7) FLASH_STAGE_K(it2 * 2 + 2, Kst[hc][0]);
    FLASH_TILE(it2 * 2 + 1, Kst[hc][1]);
  }

  // ---- in-block chunk merge ----
  // fold l across quads: lane (0,j) holds l for q = q0 + rt*16 + j
  float lf[2];
#pragma unroll
  for (int rt = 0; rt < 2; ++rt) {
    float l = lrow[rt];
    l += __shfl_xor(l, 16);
    l += __shfl_xor(l, 32);
    lf[rt] = l;
  }
  __syncthreads();  // all waves done with Kst -> safe to overlay Osh
  if (quad == 0) {
    Lsh[w][j] = lf[0];
    Lsh[w][16 + j] = lf[1];
  }
  float* Osh = (float*)&Kst[0][0][0];  // 32 KB = 4 waves x 2rt x 4dt x 4r x 64
  if (w >= 4) {
    int wb = w - 4;
#pragma unroll
    for (int rt = 0; rt < 2; ++rt)
#pragma unroll
      for (int dt = 0; dt < 4; ++dt)
#pragma unroll
        for (int r = 0; r < 4; ++r)
          Osh[((((wb * 2 + rt) * 4 + dt) * 4) + r) * 64 + lane] = oacc[rt][dt][r];
  }
  __syncthreads();  // Osh + Lsh visible
  if (w < 4) {
    int n = nh >> 4, h = nh & 15;
    float inv[2][4];
#pragma unroll
    for (int rt = 0; rt < 2; ++rt)
#pragma unroll
      for (int r = 0; r < 4; ++r) {
        int idx = rt * 16 + quad * 4 + r;
        inv[rt][r] = 1.0f / (Lsh[w][idx] + Lsh[w + 4][idx]);
      }
#pragma unroll
    for (int rt = 0; rt < 2; ++rt)
#pragma unroll
      for (int r = 0; r < 4; ++r) {
        int s = q0 + rt * 16 + quad * 4 + r;
        size_t base = ((size_t)(n * 2048 + s)) * 1024 + h * 64;
#pragma unroll
        for (int dt = 0; dt < 4; ++dt) {
          float o = oacc[rt][dt][r] +
                    Osh[((((w * 2 + rt) * 4 + dt) * 4) + r) * 64 + lane];
          attn[base + dt * 16 + j] = (bf16)(o * inv[rt][r]);
        }
      }
  }
}

extern "C" void kernel_launch(void* const* d_in, const int* in_sizes, int n_in,
                              void* d_out, int out_size, void* d_ws, size_t ws_size,
                              hipStream_t stream) {
  const float* x = (const float*)d_in[0];
  const float* head_mask = (const float*)d_in[1];
  const float* qkv_w = (const float*)d_in[2];
  const float* qkv_b = (const float*)d_in[3];
  const float* fc_w = (const float*)d_in[4];
  const float* fc_b = (const float*)d_in[5];
  float* out = (float*)d_out;

  char* ws = (char*)d_ws;
  bf16* x_bf    = (bf16*)(ws + 0);                    // 8 MB (later reused as attn)
  bf16* qkvw_bf = (bf16*)(ws + ((size_t)8 << 20));    // 6 MB
  bf16* fcw_bf  = (bf16*)(ws + ((size_t)14 << 20));   // 2 MB
  bf16* Qp      = (bf16*)(ws + ((size_t)16 << 20));   // 8 MB
  bf16* Kf      = (bf16*)(ws + ((size_t)24 << 20));   // 8 MB (fragment-major K, lane-local-P perm)
  bf16* Vf      = (bf16*)(ws + ((size_t)32 << 20));   // 8 MB (fragment-major V, natural order)
  bf16* attn = x_bf;              // x_bf dead after gemm1

  cvt3_kernel<<<8192, 256, 0, stream>>>(x, qkv_w, fc_w, x_bf, qkvw_bf, fcw_bf);
  gemm_bt_kernel<0><<<32 * 24, 256, 0, stream>>>(x_bf, qkvw_bf, qkv_b, head_mask,
                                                 Qp, Kf, Vf, nullptr, 3072, 1024, 32);
  flash_kernel<<<512, 512, 0, stream>>>(Qp, Kf, Vf, attn);
  gemm_bt_kernel<1><<<32 * 8, 256, 0, stream>>>(attn, fcw_bf, fc_b, nullptr,
                                                nullptr, nullptr, nullptr, out, 1024, 1024, 32);
}

// Round 12
// 189.053 us; speedup vs baseline: 2.3581x; 1.0587x over previous
//
#include <hip/hip_runtime.h>
#include <hip/hip_bf16.h>

typedef __bf16 bf16;
typedef __attribute__((ext_vector_type(8))) __bf16 bf16x8;
typedef __attribute__((ext_vector_type(4))) __bf16 bf16x4;
typedef __attribute__((ext_vector_type(4))) float f32x4;
typedef __attribute__((ext_vector_type(4))) unsigned int uint4x;

#if __has_builtin(__builtin_amdgcn_exp2f)
#define EXP2F(x) __builtin_amdgcn_exp2f(x)
#else
#define EXP2F(x) exp2f(x)
#endif

#define AS1 __attribute__((address_space(1)))
#define AS3 __attribute__((address_space(3)))

static __device__ __forceinline__ void async_ld16(const bf16* g, bf16* l) {
  __builtin_amdgcn_global_load_lds((const AS1 void*)g, (AS3 void*)l, 16, 0, 0);
}

// f32 -> bf16 with EXPLICIT round-to-nearest-even bit arithmetic (proven in
// round 4: cvt_pk-based paths failed at ~9e-3; this passes at 2.4e-3).
// Valid for positive finite inputs (exp2 output); no NaN handling needed.
static __device__ __forceinline__ unsigned bf16rne(float x) {
  unsigned u = __float_as_uint(x);
  return (u + 0x7fffu + ((u >> 16) & 1u)) >> 16;
}
static __device__ __forceinline__ unsigned pack2(float a, float b) {
  return bf16rne(a) | (bf16rne(b) << 16);
}

// ---------------- fused fp32 -> bf16 conversion (x, qkv_w, fc_w) ----------
__global__ void cvt3_kernel(const float* __restrict__ x, const float* __restrict__ qw,
                            const float* __restrict__ fw, bf16* __restrict__ xb,
                            bf16* __restrict__ qwb, bf16* __restrict__ fwb) {
  int b = blockIdx.x;
  const float* src;
  bf16* dst;
  int i;
  if (b < 4096) { src = x; dst = xb; i = b * 256 + threadIdx.x; }
  else if (b < 7168) { src = qw; dst = qwb; i = (b - 4096) * 256 + threadIdx.x; }
  else { src = fw; dst = fwb; i = (b - 7168) * 256 + threadIdx.x; }
  f32x4 v = *(const f32x4*)(src + (size_t)i * 4);
  bf16x4 o;
  o[0] = (bf16)v[0]; o[1] = (bf16)v[1]; o[2] = (bf16)v[2]; o[3] = (bf16)v[3];
  *(bf16x4*)(dst + (size_t)i * 4) = o;
}

// ---------------- BT-GEMM: C[M,N] = A[M,K] @ B[N,K]^T ----------------
// (byte-identical to the passing rounds 8/9: 2-phase double-buffer + T2
// pre-swizzled-source XOR swizzle on the fragment reads.)
// MODE 0 epilogue: bias + head_mask; Q -> [nh][s][d] (x log2(e)/8);
//   K -> fragment-major Kf with the LANE-LOCAL-P permutation baked in
//     (key g at C-tile ct = 2*(g>>5)+((g>>2)&1), row i = ((g>>3)&3)*4+(g&3));
//   V -> natural fragment-major Vf. Both key-linear at 64-key granularity.
// MODE 1: fp32 out = acc + bias.
#define GEMM_STAGE(k0_, buf_)                                                    \
  {                                                                              \
    async_ld16(A + (size_t)(rowBase + r0) * Kdim + (k0_) + csw, &As[buf_][f0]);  \
    async_ld16(A + (size_t)(rowBase + r1) * Kdim + (k0_) + csw, &As[buf_][f1]);  \
    async_ld16(Bw + (size_t)(colBase + r0) * Kdim + (k0_) + csw, &Bs[buf_][f0]); \
    async_ld16(Bw + (size_t)(colBase + r1) * Kdim + (k0_) + csw, &Bs[buf_][f1]); \
  }

template <int MODE>
__global__ __launch_bounds__(256, 2) void gemm_bt_kernel(
    const bf16* __restrict__ A, const bf16* __restrict__ Bw,
    const float* __restrict__ bias, const float* __restrict__ hm,
    bf16* __restrict__ Qp, bf16* __restrict__ Kp, bf16* __restrict__ Vp,
    float* __restrict__ outF, int Ncols, int Kdim, int rowBlkCount) {
  __shared__ bf16 As[2][128 * 32];
  __shared__ bf16 Bs[2][128 * 32];
  const int t = threadIdx.x, lane = t & 63, w = t >> 6;
  const int wr = w >> 1, wc = w & 1;
  const int j = lane & 15, quad = lane >> 4;
  const int rowBlk = blockIdx.x % rowBlkCount;
  const int colBlk = blockIdx.x / rowBlkCount;
  const int rowBase = rowBlk * 128, colBase = colBlk * 128;

  f32x4 acc[4][4];
  const f32x4 z4 = {0.f, 0.f, 0.f, 0.f};
#pragma unroll
  for (int i = 0; i < 4; ++i)
#pragma unroll
    for (int jj = 0; jj < 4; ++jj) acc[i][jj] = z4;

  const int f0 = t * 8;
  const int f1 = f0 + 2048;
  const int r0 = f0 >> 5, r1 = r0 + 64;
  const int csw = (((t & 3) ^ ((r0 >> 1) & 3))) * 8;
  const int qsw = (quad ^ ((j >> 1) & 3)) * 8;

  GEMM_STAGE(0, 0);
  int buf = 0;
  for (int k0 = 0; k0 < Kdim; k0 += 32) {
    __syncthreads();  // buf staged; all waves done reading buf^1
    if (k0 + 32 < Kdim) GEMM_STAGE(k0 + 32, buf ^ 1);  // overlaps compute below
    bf16x8 af[4], bfr[4];
#pragma unroll
    for (int i = 0; i < 4; ++i)
      af[i] = *(const bf16x8*)&As[buf][(wr * 64 + i * 16 + j) * 32 + qsw];
#pragma unroll
    for (int jj = 0; jj < 4; ++jj)
      bfr[jj] = *(const bf16x8*)&Bs[buf][(wc * 64 + jj * 16 + j) * 32 + qsw];
#pragma unroll
    for (int i = 0; i < 4; ++i)
#pragma unroll
      for (int jj = 0; jj < 4; ++jj)
        acc[i][jj] = __builtin_amdgcn_mfma_f32_16x16x32_bf16(af[i], bfr[jj], acc[i][jj], 0, 0, 0);
    buf ^= 1;
  }

  if (MODE == 0) {
#pragma unroll
    for (int jj = 0; jj < 4; ++jj) {
      int col = colBase + wc * 64 + jj * 16 + j;
      int hh = col / 192;
      int rem = col - hh * 192;
      int mm = rem >> 6;   // wave-uniform (16-col runs never cross a 64 boundary)
      int dd = rem & 63;
      float hmv = hm[hh];
      float bv = bias[col];
      float sc = (mm == 0) ? hmv * 0.18033688011112042f : hmv;  // log2(e)/8 folded into Q
#pragma unroll
      for (int i = 0; i < 4; ++i) {
#pragma unroll
        for (int r = 0; r < 4; ++r) {
          int row = rowBase + wr * 64 + i * 16 + quad * 4 + r;
          int n = row >> 11, ss = row & 2047;
          size_t nh = (size_t)(n * 16 + hh);
          float val = (acc[i][jj][r] + bv) * sc;
          if (mm == 0) {
            Qp[nh * 131072 + ss * 64 + dd] = (bf16)val;
          } else if (mm == 1) {
            // lane-local-P Kf: g = ss&127, T = ss>>7,
            // ct = 2*((g>>5)&3) + ((g>>2)&1), i = ((g>>3)&3)*4 + (g&3)
            size_t idx = nh * 131072 + (size_t)(ss >> 7) * 8192 +
                         (size_t)(2 * ((ss >> 5) & 3) + ((ss >> 2) & 1)) * 1024 +
                         (dd >> 5) * 512 + ((dd >> 3) & 3) * 128 +
                         (((ss >> 3) & 3) * 4 + (ss & 3)) * 8 + (dd & 7);
            Kp[idx] = (bf16)val;
          } else {
            // natural fragment-major V: tile (ss>>7), block (kk=(ss>>5)&3, dt=dd>>4),
            // within block quad=(ss>>3)&3, j=dd&15, elem=ss&7
            size_t idx = nh * 131072 + (size_t)(ss >> 7) * 8192 +
                         (((ss >> 5) & 3) * 4 + (dd >> 4)) * 512 +
                         ((ss >> 3) & 3) * 128 + (dd & 15) * 8 + (ss & 7);
            Vp[idx] = (bf16)val;
          }
        }
      }
    }
  } else {
#pragma unroll
    for (int jj = 0; jj < 4; ++jj) {
      int col = colBase + wc * 64 + jj * 16 + j;
      float bv = bias[col];
#pragma unroll
      for (int i = 0; i < 4; ++i)
#pragma unroll
        for (int r = 0; r < 4; ++r) {
          int row = rowBase + wr * 64 + i * 16 + quad * 4 + r;
          outF[(size_t)row * Ncols + col] = acc[i][jj][r] + bv;
        }
    }
  }
}

// ---------------- Flash attention: 8-wave block, in-block merge (round 9) ---
// ROUND-12: round-11 post-mortem — V-direct regressed at equal occupancy
// (55.2 -> 62.3 us): L2 V-load latency sits inside the PV loop, serialized
// with MFMAs, while LDS-staged V rides the barrier-hidden async pipeline.
// V-direct disproven in both occupancy regimes -> REVERT to the round-9
// structure (best measured: V double-buffered in LDS, in-block chunk merge).
// ONE new variable: T5 s_setprio(1) around the MFMA clusters (m191: +4-7%
// on attn kernels with wave role diversity; our 8 waves hit MFMA regions
// staggered across the two chunk-halves). Scheduler hint only — values and
// sync structure bit-identical to round 9.
#define FLASH_STAGE(tileIdx, KsBuf, VsBuf)                                  \
  {                                                                         \
    const bf16* kn_ = Kc + (tileIdx) * 4096;                                \
    const bf16* vn_ = Vc + (tileIdx) * 4096;                                \
    _Pragma("unroll")                                                       \
    for (int p = 0; p < 2; ++p) {                                           \
      int c = (p * 256 + ts) * 8;                                           \
      async_ld16(kn_ + c, &(KsBuf)[c]);                                     \
      async_ld16(vn_ + c, &(VsBuf)[c]);                                     \
    }                                                                       \
  }

#define FLASH_TILE(KsBuf, VsBuf)                                            \
  {                                                                         \
    unsigned pkd[2][4][2];                                                  \
    _Pragma("unroll")                                                       \
    for (int ct = 0; ct < 4; ++ct) {                                        \
      bf16x8 kf0 = *(const bf16x8*)&(KsBuf)[ct * 1024 + lane * 8];          \
      bf16x8 kf1 = *(const bf16x8*)&(KsBuf)[ct * 1024 + 512 + lane * 8];    \
      _Pragma("unroll")                                                     \
      for (int rt = 0; rt < 2; ++rt) {                                      \
        f32x4 sv = z4;                                                      \
        __builtin_amdgcn_s_setprio(1);                                      \
        sv = __builtin_amdgcn_mfma_f32_16x16x32_bf16(kf0, qf[rt][0], sv, 0, 0, 0); \
        sv = __builtin_amdgcn_mfma_f32_16x16x32_bf16(kf1, qf[rt][1], sv, 0, 0, 0); \
        __builtin_amdgcn_s_setprio(0);                                      \
        float p0 = EXP2F(sv[0]), p1 = EXP2F(sv[1]);                         \
        float p2 = EXP2F(sv[2]), p3 = EXP2F(sv[3]);                         \
        lrow[rt] += (p0 + p1) + (p2 + p3);                                  \
        pkd[rt][ct][0] = pack2(p0, p1);                                     \
        pkd[rt][ct][1] = pack2(p2, p3);                                     \
      }                                                                     \
    }                                                                       \
    __builtin_amdgcn_s_setprio(1);                                          \
    _Pragma("unroll")                                                       \
    for (int kk = 0; kk < 2; ++kk) {                                        \
      union { uint4x u; bf16x8 h; } pa[2];                                  \
      _Pragma("unroll")                                                     \
      for (int rt = 0; rt < 2; ++rt)                                        \
        pa[rt].u = (uint4x){pkd[rt][2 * kk][0], pkd[rt][2 * kk][1],         \
                            pkd[rt][2 * kk + 1][0], pkd[rt][2 * kk + 1][1]};\
      _Pragma("unroll")                                                     \
      for (int dt = 0; dt < 4; ++dt) {                                      \
        bf16x8 vf = *(const bf16x8*)&(VsBuf)[(kk * 4 + dt) * 512 + lane * 8]; \
        oacc[0][dt] = __builtin_amdgcn_mfma_f32_16x16x32_bf16(pa[0].h, vf, oacc[0][dt], 0, 0, 0); \
        oacc[1][dt] = __builtin_amdgcn_mfma_f32_16x16x32_bf16(pa[1].h, vf, oacc[1][dt], 0, 0, 0); \
      }                                                                     \
    }                                                                       \
    __builtin_amdgcn_s_setprio(0);                                          \
  }

__global__ __launch_bounds__(512, 4) void flash_kernel(const bf16* __restrict__ Qp,
                                                       const bf16* __restrict__ Kf,
                                                       const bf16* __restrict__ Vf,
                                                       bf16* __restrict__ attn) {
  __shared__ bf16 Kst[2][2][4096];   // [chunk][buf][..]  32 KB (Osh overlays)
  __shared__ bf16 Vst[2][2][4096];   // 32 KB
  __shared__ float Lsh[8][32];       // per-wave folded l  1 KB
  const int t = threadIdx.x, lane = t & 63, w = t >> 6;
  const int ts = t & 255;            // thread id within chunk-half
  const int hc = t >> 8;             // chunk (0: waves 0-3, 1: waves 4-7)
  const int j = lane & 15, quad = lane >> 4;
  const int b = blockIdx.x;
  const int qt = b >> 5;             // [0,16)
  const int nh = b & 31;
  const int q0 = qt * 128 + (w & 3) * 32;
  const bf16* Qb = Qp + (size_t)nh * 131072;
  const bf16* Kc = Kf + (size_t)nh * 131072 + hc * 65536;
  const bf16* Vc = Vf + (size_t)nh * 131072 + hc * 65536;

  bf16x8 qf[2][2];
#pragma unroll
  for (int rt = 0; rt < 2; ++rt)
#pragma unroll
    for (int kd = 0; kd < 2; ++kd)
      qf[rt][kd] = *(const bf16x8*)&Qb[(size_t)(q0 + rt * 16 + j) * 64 + kd * 32 + quad * 8];

  float lrow[2] = {0.f, 0.f};
  f32x4 oacc[2][4];
  const f32x4 z4 = {0.f, 0.f, 0.f, 0.f};
#pragma unroll
  for (int rt = 0; rt < 2; ++rt)
#pragma unroll
    for (int dt = 0; dt < 4; ++dt) oacc[rt][dt] = z4;

  // prologue: stage sub-tile 0 into buffer 0 (only this one is unoverlapped)
  FLASH_STAGE(0, Kst[hc][0], Vst[hc][0]);

  for (int it2 = 0; it2 < 8; ++it2) {
    __syncthreads();  // drains buf0 staging; all waves done reading buf1
    FLASH_STAGE(it2 * 2 + 1, Kst[hc][1], Vst[hc][1]);   // overlaps compute
    FLASH_TILE(Kst[hc][0], Vst[hc][0]);
    __syncthreads();  // drains buf1 staging; all waves done reading buf0
    if (it2 < 7) FLASH_STAGE(it2 * 2 + 2, Kst[hc][0], Vst[hc][0]);
    FLASH_TILE(Kst[hc][1], Vst[hc][1]);
  }

  // ---- in-block chunk merge ----
  // fold l across quads: lane (0,j) holds l for q = q0 + rt*16 + j
  float lf[2];
#pragma unroll
  for (int rt = 0; rt < 2; ++rt) {
    float l = lrow[rt];
    l += __shfl_xor(l, 16);
    l += __shfl_xor(l, 32);
    lf[rt] = l;
  }
  __syncthreads();  // all waves done with Kst/Vst -> safe to overlay Osh
  if (quad == 0) {
    Lsh[w][j] = lf[0];
    Lsh[w][16 + j] = lf[1];
  }
  float* Osh = (float*)&Kst[0][0][0];  // 32 KB = 4 waves x 2rt x 4dt x 4r x 64
  if (w >= 4) {
    int wb = w - 4;
#pragma unroll
    for (int rt = 0; rt < 2; ++rt)
#pragma unroll
      for (int dt = 0; dt < 4; ++dt)
#pragma unroll
        for (int r = 0; r < 4; ++r)
          Osh[((((wb * 2 + rt) * 4 + dt) * 4) + r) * 64 + lane] = oacc[rt][dt][r];
  }
  __syncthreads();  // Osh + Lsh visible
  if (w < 4) {
    int n = nh >> 4, h = nh & 15;
    float inv[2][4];
#pragma unroll
    for (int rt = 0; rt < 2; ++rt)
#pragma unroll
      for (int r = 0; r < 4; ++r) {
        int idx = rt * 16 + quad * 4 + r;
        inv[rt][r] = 1.0f / (Lsh[w][idx] + Lsh[w + 4][idx]);
      }
#pragma unroll
    for (int rt = 0; rt < 2; ++rt)
#pragma unroll
      for (int r = 0; r < 4; ++r) {
        int s = q0 + rt * 16 + quad * 4 + r;
        size_t base = ((size_t)(n * 2048 + s)) * 1024 + h * 64;
#pragma unroll
        for (int dt = 0; dt < 4; ++dt) {
          float o = oacc[rt][dt][r] +
                    Osh[((((w * 2 + rt) * 4 + dt) * 4) + r) * 64 + lane];
          attn[base + dt * 16 + j] = (bf16)(o * inv[rt][r]);
        }
      }
  }
}

extern "C" void kernel_launch(void* const* d_in, const int* in_sizes, int n_in,
                              void* d_out, int out_size, void* d_ws, size_t ws_size,
                              hipStream_t stream) {
  const float* x = (const float*)d_in[0];
  const float* head_mask = (const float*)d_in[1];
  const float* qkv_w = (const float*)d_in[2];
  const float* qkv_b = (const float*)d_in[3];
  const float* fc_w = (const float*)d_in[4];
  const float* fc_b = (const float*)d_in[5];
  float* out = (float*)d_out;

  char* ws = (char*)d_ws;
  bf16* x_bf    = (bf16*)(ws + 0);                    // 8 MB (later reused as attn)
  bf16* qkvw_bf = (bf16*)(ws + ((size_t)8 << 20));    // 6 MB
  bf16* fcw_bf  = (bf16*)(ws + ((size_t)14 << 20));   // 2 MB
  bf16* Qp      = (bf16*)(ws + ((size_t)16 << 20));   // 8 MB
  bf16* Kf      = (bf16*)(ws + ((size_t)24 << 20));   // 8 MB (fragment-major K, lane-local-P perm)
  bf16* Vf      = (bf16*)(ws + ((size_t)32 << 20));   // 8 MB (fragment-major V, natural order)
  bf16* attn = x_bf;              // x_bf dead after gemm1

  cvt3_kernel<<<8192, 256, 0, stream>>>(x, qkv_w, fc_w, x_bf, qkvw_bf, fcw_bf);
  gemm_bt_kernel<0><<<32 * 24, 256, 0, stream>>>(x_bf, qkvw_bf, qkv_b, head_mask,
                                                 Qp, Kf, Vf, nullptr, 3072, 1024, 32);
  flash_kernel<<<512, 512, 0, stream>>>(Qp, Kf, Vf, attn);
  gemm_bt_kernel<1><<<32 * 8, 256, 0, stream>>>(attn, fcw_bf, fc_b, nullptr,
                                                nullptr, nullptr, nullptr, out, 1024, 1024, 32);
}

// Round 13
// 185.296 us; speedup vs baseline: 2.4059x; 1.0203x over previous
//
#include <hip/hip_runtime.h>
#include <hip/hip_bf16.h>

typedef __bf16 bf16;
typedef __attribute__((ext_vector_type(8))) __bf16 bf16x8;
typedef __attribute__((ext_vector_type(4))) __bf16 bf16x4;
typedef __attribute__((ext_vector_type(4))) float f32x4;
typedef __attribute__((ext_vector_type(4))) unsigned int uint4x;

#if __has_builtin(__builtin_amdgcn_exp2f)
#define EXP2F(x) __builtin_amdgcn_exp2f(x)
#else
#define EXP2F(x) exp2f(x)
#endif

#define AS1 __attribute__((address_space(1)))
#define AS3 __attribute__((address_space(3)))

static __device__ __forceinline__ void async_ld16(const bf16* g, bf16* l) {
  __builtin_amdgcn_global_load_lds((const AS1 void*)g, (AS3 void*)l, 16, 0, 0);
}

// f32 -> bf16 with EXPLICIT round-to-nearest-even bit arithmetic (proven in
// round 4: cvt_pk-based paths failed at ~9e-3; this passes at 2.4e-3).
// Valid for positive finite inputs (exp2 output); no NaN handling needed.
static __device__ __forceinline__ unsigned bf16rne(float x) {
  unsigned u = __float_as_uint(x);
  return (u + 0x7fffu + ((u >> 16) & 1u)) >> 16;
}
static __device__ __forceinline__ unsigned pack2(float a, float b) {
  return bf16rne(a) | (bf16rne(b) << 16);
}

// ---------------- fused fp32 -> bf16 conversion (x, qkv_w, fc_w) ----------
__global__ void cvt3_kernel(const float* __restrict__ x, const float* __restrict__ qw,
                            const float* __restrict__ fw, bf16* __restrict__ xb,
                            bf16* __restrict__ qwb, bf16* __restrict__ fwb) {
  int b = blockIdx.x;
  const float* src;
  bf16* dst;
  int i;
  if (b < 4096) { src = x; dst = xb; i = b * 256 + threadIdx.x; }
  else if (b < 7168) { src = qw; dst = qwb; i = (b - 4096) * 256 + threadIdx.x; }
  else { src = fw; dst = fwb; i = (b - 7168) * 256 + threadIdx.x; }
  f32x4 v = *(const f32x4*)(src + (size_t)i * 4);
  bf16x4 o;
  o[0] = (bf16)v[0]; o[1] = (bf16)v[1]; o[2] = (bf16)v[2]; o[3] = (bf16)v[3];
  *(bf16x4*)(dst + (size_t)i * 4) = o;
}

// ---------------- BT-GEMM: C[M,N] = A[M,K] @ B[N,K]^T ----------------
// ROUND-13 CHANGE (one variable): T4 counted-vmcnt + raw s_barrier K-loop
// (m201/m218 pattern). Round-12 counters: gemm1 = top dispatch (57.2us,
// MfmaUtil 16.7 / VALU 16.5 / HBM 12 / occ 30 -- latency-bound at 451 TF vs
// ~900 TF for the same structure on 4096^3). Cause: __syncthreads drains
// vmcnt(0) at EVERY barrier, capping the staging hide-window at one compute
// phase regardless of buffer depth (m97-ceiling mechanism). Fix: distance-2
// staging + per-iteration {vmcnt(4); s_barrier; sched_barrier(0)} so this
// tile's loads (issued TWO phases ago) are waited while the next tile's 4
// loads stay in flight across the barrier; second raw barrier (all waves'
// ds_reads complete before their MFMAs issue) guards the buffer overwrite.
// In-flight ledger: 8 at each wait, 4 after; final iteration vmcnt(0).
// Staging values/order byte-identical -> absmax unchanged.
// (T2 pre-swizzled-source XOR on fragment reads retained from round 8.)
// MODE 0 epilogue: bias + head_mask; Q -> [nh][s][d] (x log2(e)/8);
//   K -> fragment-major Kf with the LANE-LOCAL-P permutation baked in
//     (key g at C-tile ct = 2*(g>>5)+((g>>2)&1), row i = ((g>>3)&3)*4+(g&3));
//   V -> natural fragment-major Vf. Both key-linear at 64-key granularity.
// MODE 1: fp32 out = acc + bias.
#define GEMM_STAGE(k0_, buf_)                                                    \
  {                                                                              \
    async_ld16(A + (size_t)(rowBase + r0) * Kdim + (k0_) + csw, &As[buf_][f0]);  \
    async_ld16(A + (size_t)(rowBase + r1) * Kdim + (k0_) + csw, &As[buf_][f1]);  \
    async_ld16(Bw + (size_t)(colBase + r0) * Kdim + (k0_) + csw, &Bs[buf_][f0]); \
    async_ld16(Bw + (size_t)(colBase + r1) * Kdim + (k0_) + csw, &Bs[buf_][f1]); \
  }

template <int MODE>
__global__ __launch_bounds__(256, 2) void gemm_bt_kernel(
    const bf16* __restrict__ A, const bf16* __restrict__ Bw,
    const float* __restrict__ bias, const float* __restrict__ hm,
    bf16* __restrict__ Qp, bf16* __restrict__ Kp, bf16* __restrict__ Vp,
    float* __restrict__ outF, int Ncols, int Kdim, int rowBlkCount) {
  __shared__ bf16 As[2][128 * 32];
  __shared__ bf16 Bs[2][128 * 32];
  const int t = threadIdx.x, lane = t & 63, w = t >> 6;
  const int wr = w >> 1, wc = w & 1;
  const int j = lane & 15, quad = lane >> 4;
  const int rowBlk = blockIdx.x % rowBlkCount;
  const int colBlk = blockIdx.x / rowBlkCount;
  const int rowBase = rowBlk * 128, colBase = colBlk * 128;

  f32x4 acc[4][4];
  const f32x4 z4 = {0.f, 0.f, 0.f, 0.f};
#pragma unroll
  for (int i = 0; i < 4; ++i)
#pragma unroll
    for (int jj = 0; jj < 4; ++jj) acc[i][jj] = z4;

  const int f0 = t * 8;
  const int f1 = f0 + 2048;
  const int r0 = f0 >> 5, r1 = r0 + 64;
  const int csw = (((t & 3) ^ ((r0 >> 1) & 3))) * 8;
  const int qsw = (quad ^ ((j >> 1) & 3)) * 8;

  // distance-2 prologue: tiles 0 and 1 in flight (8 loads/thread)
  GEMM_STAGE(0, 0);
  if (32 < Kdim) GEMM_STAGE(32, 1);
  int buf = 0;
  for (int k0 = 0; k0 < Kdim; k0 += 32) {
    // wait only THIS tile's 4 loads (oldest); next tile's stay in flight
    if (k0 + 32 < Kdim) {
      asm volatile("s_waitcnt vmcnt(4)" ::: "memory");
    } else {
      asm volatile("s_waitcnt vmcnt(0)" ::: "memory");
    }
    __builtin_amdgcn_s_barrier();        // all waves' tile loads complete
    __builtin_amdgcn_sched_barrier(0);   // rule #18: pin ds_reads after wait
    bf16x8 af[4], bfr[4];
#pragma unroll
    for (int i = 0; i < 4; ++i)
      af[i] = *(const bf16x8*)&As[buf][(wr * 64 + i * 16 + j) * 32 + qsw];
#pragma unroll
    for (int jj = 0; jj < 4; ++jj)
      bfr[jj] = *(const bf16x8*)&Bs[buf][(wc * 64 + jj * 16 + j) * 32 + qsw];
#pragma unroll
    for (int i = 0; i < 4; ++i)
#pragma unroll
      for (int jj = 0; jj < 4; ++jj)
        acc[i][jj] = __builtin_amdgcn_mfma_f32_16x16x32_bf16(af[i], bfr[jj], acc[i][jj], 0, 0, 0);
    __builtin_amdgcn_s_barrier();        // all waves done reading buf
    __builtin_amdgcn_sched_barrier(0);   // keep re-stage below the barrier
    if (k0 + 64 < Kdim) GEMM_STAGE(k0 + 64, buf);  // overwrite safe now
    buf ^= 1;
  }

  if (MODE == 0) {
#pragma unroll
    for (int jj = 0; jj < 4; ++jj) {
      int col = colBase + wc * 64 + jj * 16 + j;
      int hh = col / 192;
      int rem = col - hh * 192;
      int mm = rem >> 6;   // wave-uniform (16-col runs never cross a 64 boundary)
      int dd = rem & 63;
      float hmv = hm[hh];
      float bv = bias[col];
      float sc = (mm == 0) ? hmv * 0.18033688011112042f : hmv;  // log2(e)/8 folded into Q
#pragma unroll
      for (int i = 0; i < 4; ++i) {
#pragma unroll
        for (int r = 0; r < 4; ++r) {
          int row = rowBase + wr * 64 + i * 16 + quad * 4 + r;
          int n = row >> 11, ss = row & 2047;
          size_t nh = (size_t)(n * 16 + hh);
          float val = (acc[i][jj][r] + bv) * sc;
          if (mm == 0) {
            Qp[nh * 131072 + ss * 64 + dd] = (bf16)val;
          } else if (mm == 1) {
            // lane-local-P Kf: g = ss&127, T = ss>>7,
            // ct = 2*((g>>5)&3) + ((g>>2)&1), i = ((g>>3)&3)*4 + (g&3)
            size_t idx = nh * 131072 + (size_t)(ss >> 7) * 8192 +
                         (size_t)(2 * ((ss >> 5) & 3) + ((ss >> 2) & 1)) * 1024 +
                         (dd >> 5) * 512 + ((dd >> 3) & 3) * 128 +
                         (((ss >> 3) & 3) * 4 + (ss & 3)) * 8 + (dd & 7);
            Kp[idx] = (bf16)val;
          } else {
            // natural fragment-major V: tile (ss>>7), block (kk=(ss>>5)&3, dt=dd>>4),
            // within block quad=(ss>>3)&3, j=dd&15, elem=ss&7
            size_t idx = nh * 131072 + (size_t)(ss >> 7) * 8192 +
                         (((ss >> 5) & 3) * 4 + (dd >> 4)) * 512 +
                         ((ss >> 3) & 3) * 128 + (dd & 15) * 8 + (ss & 7);
            Vp[idx] = (bf16)val;
          }
        }
      }
    }
  } else {
#pragma unroll
    for (int jj = 0; jj < 4; ++jj) {
      int col = colBase + wc * 64 + jj * 16 + j;
      float bv = bias[col];
#pragma unroll
      for (int i = 0; i < 4; ++i)
#pragma unroll
        for (int r = 0; r < 4; ++r) {
          int row = rowBase + wr * 64 + i * 16 + quad * 4 + r;
          outF[(size_t)row * Ncols + col] = acc[i][jj][r] + bv;
        }
    }
  }
}

// ---------------- Flash attention: 8-wave block, in-block merge + setprio ---
// (unchanged from the passing round 12: round-9 structure + T5 s_setprio.)
#define FLASH_STAGE(tileIdx, KsBuf, VsBuf)                                  \
  {                                                                         \
    const bf16* kn_ = Kc + (tileIdx) * 4096;                                \
    const bf16* vn_ = Vc + (tileIdx) * 4096;                                \
    _Pragma("unroll")                                                       \
    for (int p = 0; p < 2; ++p) {                                           \
      int c = (p * 256 + ts) * 8;                                           \
      async_ld16(kn_ + c, &(KsBuf)[c]);                                     \
      async_ld16(vn_ + c, &(VsBuf)[c]);                                     \
    }                                                                       \
  }

#define FLASH_TILE(KsBuf, VsBuf)                                            \
  {                                                                         \
    unsigned pkd[2][4][2];                                                  \
    _Pragma("unroll")                                                       \
    for (int ct = 0; ct < 4; ++ct) {                                        \
      bf16x8 kf0 = *(const bf16x8*)&(KsBuf)[ct * 1024 + lane * 8];          \
      bf16x8 kf1 = *(const bf16x8*)&(KsBuf)[ct * 1024 + 512 + lane * 8];    \
      _Pragma("unroll")                                                     \
      for (int rt = 0; rt < 2; ++rt) {                                      \
        f32x4 sv = z4;                                                      \
        __builtin_amdgcn_s_setprio(1);                                      \
        sv = __builtin_amdgcn_mfma_f32_16x16x32_bf16(kf0, qf[rt][0], sv, 0, 0, 0); \
        sv = __builtin_amdgcn_mfma_f32_16x16x32_bf16(kf1, qf[rt][1], sv, 0, 0, 0); \
        __builtin_amdgcn_s_setprio(0);                                      \
        float p0 = EXP2F(sv[0]), p1 = EXP2F(sv[1]);                         \
        float p2 = EXP2F(sv[2]), p3 = EXP2F(sv[3]);                         \
        lrow[rt] += (p0 + p1) + (p2 + p3);                                  \
        pkd[rt][ct][0] = pack2(p0, p1);                                     \
        pkd[rt][ct][1] = pack2(p2, p3);                                     \
      }                                                                     \
    }                                                                       \
    __builtin_amdgcn_s_setprio(1);                                          \
    _Pragma("unroll")                                                       \
    for (int kk = 0; kk < 2; ++kk) {                                        \
      union { uint4x u; bf16x8 h; } pa[2];                                  \
      _Pragma("unroll")                                                     \
      for (int rt = 0; rt < 2; ++rt)                                        \
        pa[rt].u = (uint4x){pkd[rt][2 * kk][0], pkd[rt][2 * kk][1],         \
                            pkd[rt][2 * kk + 1][0], pkd[rt][2 * kk + 1][1]};\
      _Pragma("unroll")                                                     \
      for (int dt = 0; dt < 4; ++dt) {                                      \
        bf16x8 vf = *(const bf16x8*)&(VsBuf)[(kk * 4 + dt) * 512 + lane * 8]; \
        oacc[0][dt] = __builtin_amdgcn_mfma_f32_16x16x32_bf16(pa[0].h, vf, oacc[0][dt], 0, 0, 0); \
        oacc[1][dt] = __builtin_amdgcn_mfma_f32_16x16x32_bf16(pa[1].h, vf, oacc[1][dt], 0, 0, 0); \
      }                                                                     \
    }                                                                       \
    __builtin_amdgcn_s_setprio(0);                                          \
  }

__global__ __launch_bounds__(512, 4) void flash_kernel(const bf16* __restrict__ Qp,
                                                       const bf16* __restrict__ Kf,
                                                       const bf16* __restrict__ Vf,
                                                       bf16* __restrict__ attn) {
  __shared__ bf16 Kst[2][2][4096];   // [chunk][buf][..]  32 KB (Osh overlays)
  __shared__ bf16 Vst[2][2][4096];   // 32 KB
  __shared__ float Lsh[8][32];       // per-wave folded l  1 KB
  const int t = threadIdx.x, lane = t & 63, w = t >> 6;
  const int ts = t & 255;            // thread id within chunk-half
  const int hc = t >> 8;             // chunk (0: waves 0-3, 1: waves 4-7)
  const int j = lane & 15, quad = lane >> 4;
  const int b = blockIdx.x;
  const int qt = b >> 5;             // [0,16)
  const int nh = b & 31;
  const int q0 = qt * 128 + (w & 3) * 32;
  const bf16* Qb = Qp + (size_t)nh * 131072;
  const bf16* Kc = Kf + (size_t)nh * 131072 + hc * 65536;
  const bf16* Vc = Vf + (size_t)nh * 131072 + hc * 65536;

  bf16x8 qf[2][2];
#pragma unroll
  for (int rt = 0; rt < 2; ++rt)
#pragma unroll
    for (int kd = 0; kd < 2; ++kd)
      qf[rt][kd] = *(const bf16x8*)&Qb[(size_t)(q0 + rt * 16 + j) * 64 + kd * 32 + quad * 8];

  float lrow[2] = {0.f, 0.f};
  f32x4 oacc[2][4];
  const f32x4 z4 = {0.f, 0.f, 0.f, 0.f};
#pragma unroll
  for (int rt = 0; rt < 2; ++rt)
#pragma unroll
    for (int dt = 0; dt < 4; ++dt) oacc[rt][dt] = z4;

  // prologue: stage sub-tile 0 into buffer 0 (only this one is unoverlapped)
  FLASH_STAGE(0, Kst[hc][0], Vst[hc][0]);

  for (int it2 = 0; it2 < 8; ++it2) {
    __syncthreads();  // drains buf0 staging; all waves done reading buf1
    FLASH_STAGE(it2 * 2 + 1, Kst[hc][1], Vst[hc][1]);   // overlaps compute
    FLASH_TILE(Kst[hc][0], Vst[hc][0]);
    __syncthreads();  // drains buf1 staging; all waves done reading buf0
    if (it2 < 7) FLASH_STAGE(it2 * 2 + 2, Kst[hc][0], Vst[hc][0]);
    FLASH_TILE(Kst[hc][1], Vst[hc][1]);
  }

  // ---- in-block chunk merge ----
  // fold l across quads: lane (0,j) holds l for q = q0 + rt*16 + j
  float lf[2];
#pragma unroll
  for (int rt = 0; rt < 2; ++rt) {
    float l = lrow[rt];
    l += __shfl_xor(l, 16);
    l += __shfl_xor(l, 32);
    lf[rt] = l;
  }
  __syncthreads();  // all waves done with Kst/Vst -> safe to overlay Osh
  if (quad == 0) {
    Lsh[w][j] = lf[0];
    Lsh[w][16 + j] = lf[1];
  }
  float* Osh = (float*)&Kst[0][0][0];  // 32 KB = 4 waves x 2rt x 4dt x 4r x 64
  if (w >= 4) {
    int wb = w - 4;
#pragma unroll
    for (int rt = 0; rt < 2; ++rt)
#pragma unroll
      for (int dt = 0; dt < 4; ++dt)
#pragma unroll
        for (int r = 0; r < 4; ++r)
          Osh[((((wb * 2 + rt) * 4 + dt) * 4) + r) * 64 + lane] = oacc[rt][dt][r];
  }
  __syncthreads();  // Osh + Lsh visible
  if (w < 4) {
    int n = nh >> 4, h = nh & 15;
    float inv[2][4];
#pragma unroll
    for (int rt = 0; rt < 2; ++rt)
#pragma unroll
      for (int r = 0; r < 4; ++r) {
        int idx = rt * 16 + quad * 4 + r;
        inv[rt][r] = 1.0f / (Lsh[w][idx] + Lsh[w + 4][idx]);
      }
#pragma unroll
    for (int rt = 0; rt < 2; ++rt)
#pragma unroll
      for (int r = 0; r < 4; ++r) {
        int s = q0 + rt * 16 + quad * 4 + r;
        size_t base = ((size_t)(n * 2048 + s)) * 1024 + h * 64;
#pragma unroll
        for (int dt = 0; dt < 4; ++dt) {
          float o = oacc[rt][dt][r] +
                    Osh[((((w * 2 + rt) * 4 + dt) * 4) + r) * 64 + lane];
          attn[base + dt * 16 + j] = (bf16)(o * inv[rt][r]);
        }
      }
  }
}

extern "C" void kernel_launch(void* const* d_in, const int* in_sizes, int n_in,
                              void* d_out, int out_size, void* d_ws, size_t ws_size,
                              hipStream_t stream) {
  const float* x = (const float*)d_in[0];
  const float* head_mask = (const float*)d_in[1];
  const float* qkv_w = (const float*)d_in[2];
  const float* qkv_b = (const float*)d_in[3];
  const float* fc_w = (const float*)d_in[4];
  const float* fc_b = (const float*)d_in[5];
  float* out = (float*)d_out;

  char* ws = (char*)d_ws;
  bf16* x_bf    = (bf16*)(ws + 0);                    // 8 MB (later reused as attn)
  bf16* qkvw_bf = (bf16*)(ws + ((size_t)8 << 20));    // 6 MB
  bf16* fcw_bf  = (bf16*)(ws + ((size_t)14 << 20));   // 2 MB
  bf16* Qp      = (bf16*)(ws + ((size_t)16 << 20));   // 8 MB
  bf16* Kf      = (bf16*)(ws + ((size_t)24 << 20));   // 8 MB (fragment-major K, lane-local-P perm)
  bf16* Vf      = (bf16*)(ws + ((size_t)32 << 20));   // 8 MB (fragment-major V, natural order)
  bf16* attn = x_bf;              // x_bf dead after gemm1

  cvt3_kernel<<<8192, 256, 0, stream>>>(x, qkv_w, fc_w, x_bf, qkvw_bf, fcw_bf);
  gemm_bt_kernel<0><<<32 * 24, 256, 0, stream>>>(x_bf, qkvw_bf, qkv_b, head_mask,
                                                 Qp, Kf, Vf, nullptr, 3072, 1024, 32);
  flash_kernel<<<512, 512, 0, stream>>>(Qp, Kf, Vf, attn);
  gemm_bt_kernel<1><<<32 * 8, 256, 0, stream>>>(attn, fcw_bf, fc_b, nullptr,
                                                nullptr, nullptr, nullptr, out, 1024, 1024, 32);
}

// Round 14
// 185.203 us; speedup vs baseline: 2.4072x; 1.0005x over previous
//
#include <hip/hip_runtime.h>
#include <hip/hip_bf16.h>

typedef __bf16 bf16;
typedef __attribute__((ext_vector_type(8))) __bf16 bf16x8;
typedef __attribute__((ext_vector_type(4))) __bf16 bf16x4;
typedef __attribute__((ext_vector_type(4))) float f32x4;
typedef __attribute__((ext_vector_type(4))) unsigned int uint4x;

#if __has_builtin(__builtin_amdgcn_exp2f)
#define EXP2F(x) __builtin_amdgcn_exp2f(x)
#else
#define EXP2F(x) exp2f(x)
#endif

#define AS1 __attribute__((address_space(1)))
#define AS3 __attribute__((address_space(3)))

static __device__ __forceinline__ void async_ld16(const bf16* g, bf16* l) {
  __builtin_amdgcn_global_load_lds((const AS1 void*)g, (AS3 void*)l, 16, 0, 0);
}

// f32 -> bf16 with EXPLICIT round-to-nearest-even bit arithmetic (proven in
// round 4: cvt_pk-based paths failed at ~9e-3; this passes at 2.4e-3).
// Valid for positive finite inputs (exp2 output); no NaN handling needed.
static __device__ __forceinline__ unsigned bf16rne(float x) {
  unsigned u = __float_as_uint(x);
  return (u + 0x7fffu + ((u >> 16) & 1u)) >> 16;
}
static __device__ __forceinline__ unsigned pack2(float a, float b) {
  return bf16rne(a) | (bf16rne(b) << 16);
}

// ---------------- fused fp32 -> bf16 conversion (x, qkv_w, fc_w) ----------
__global__ void cvt3_kernel(const float* __restrict__ x, const float* __restrict__ qw,
                            const float* __restrict__ fw, bf16* __restrict__ xb,
                            bf16* __restrict__ qwb, bf16* __restrict__ fwb) {
  int b = blockIdx.x;
  const float* src;
  bf16* dst;
  int i;
  if (b < 4096) { src = x; dst = xb; i = b * 256 + threadIdx.x; }
  else if (b < 7168) { src = qw; dst = qwb; i = (b - 4096) * 256 + threadIdx.x; }
  else { src = fw; dst = fwb; i = (b - 7168) * 256 + threadIdx.x; }
  f32x4 v = *(const f32x4*)(src + (size_t)i * 4);
  bf16x4 o;
  o[0] = (bf16)v[0]; o[1] = (bf16)v[1]; o[2] = (bf16)v[2]; o[3] = (bf16)v[3];
  *(bf16x4*)(dst + (size_t)i * 4) = o;
}

// ---------------- BT-GEMM: C[M,N] = A[M,K] @ B[N,K]^T ----------------
// (byte-identical to the passing round 13: T4 counted-vmcnt + raw s_barrier
// distance-2 K-loop, T2 pre-swizzled-source XOR on fragment reads.)
// MODE 0 epilogue: bias + head_mask; Q -> [nh][s][d] (x log2(e)/8);
//   K -> fragment-major Kf with the LANE-LOCAL-P permutation baked in
//     (key g at C-tile ct = 2*(g>>5)+((g>>2)&1), row i = ((g>>3)&3)*4+(g&3));
//   V -> natural fragment-major Vf. Both key-linear at 32-key granularity.
// MODE 1: fp32 out = acc + bias.
#define GEMM_STAGE(k0_, buf_)                                                    \
  {                                                                              \
    async_ld16(A + (size_t)(rowBase + r0) * Kdim + (k0_) + csw, &As[buf_][f0]);  \
    async_ld16(A + (size_t)(rowBase + r1) * Kdim + (k0_) + csw, &As[buf_][f1]);  \
    async_ld16(Bw + (size_t)(colBase + r0) * Kdim + (k0_) + csw, &Bs[buf_][f0]); \
    async_ld16(Bw + (size_t)(colBase + r1) * Kdim + (k0_) + csw, &Bs[buf_][f1]); \
  }

template <int MODE>
__global__ __launch_bounds__(256, 2) void gemm_bt_kernel(
    const bf16* __restrict__ A, const bf16* __restrict__ Bw,
    const float* __restrict__ bias, const float* __restrict__ hm,
    bf16* __restrict__ Qp, bf16* __restrict__ Kp, bf16* __restrict__ Vp,
    float* __restrict__ outF, int Ncols, int Kdim, int rowBlkCount) {
  __shared__ bf16 As[2][128 * 32];
  __shared__ bf16 Bs[2][128 * 32];
  const int t = threadIdx.x, lane = t & 63, w = t >> 6;
  const int wr = w >> 1, wc = w & 1;
  const int j = lane & 15, quad = lane >> 4;
  const int rowBlk = blockIdx.x % rowBlkCount;
  const int colBlk = blockIdx.x / rowBlkCount;
  const int rowBase = rowBlk * 128, colBase = colBlk * 128;

  f32x4 acc[4][4];
  const f32x4 z4 = {0.f, 0.f, 0.f, 0.f};
#pragma unroll
  for (int i = 0; i < 4; ++i)
#pragma unroll
    for (int jj = 0; jj < 4; ++jj) acc[i][jj] = z4;

  const int f0 = t * 8;
  const int f1 = f0 + 2048;
  const int r0 = f0 >> 5, r1 = r0 + 64;
  const int csw = (((t & 3) ^ ((r0 >> 1) & 3))) * 8;
  const int qsw = (quad ^ ((j >> 1) & 3)) * 8;

  // distance-2 prologue: tiles 0 and 1 in flight (8 loads/thread)
  GEMM_STAGE(0, 0);
  if (32 < Kdim) GEMM_STAGE(32, 1);
  int buf = 0;
  for (int k0 = 0; k0 < Kdim; k0 += 32) {
    // wait only THIS tile's 4 loads (oldest); next tile's stay in flight
    if (k0 + 32 < Kdim) {
      asm volatile("s_waitcnt vmcnt(4)" ::: "memory");
    } else {
      asm volatile("s_waitcnt vmcnt(0)" ::: "memory");
    }
    __builtin_amdgcn_s_barrier();        // all waves' tile loads complete
    __builtin_amdgcn_sched_barrier(0);   // rule #18: pin ds_reads after wait
    bf16x8 af[4], bfr[4];
#pragma unroll
    for (int i = 0; i < 4; ++i)
      af[i] = *(const bf16x8*)&As[buf][(wr * 64 + i * 16 + j) * 32 + qsw];
#pragma unroll
    for (int jj = 0; jj < 4; ++jj)
      bfr[jj] = *(const bf16x8*)&Bs[buf][(wc * 64 + jj * 16 + j) * 32 + qsw];
#pragma unroll
    for (int i = 0; i < 4; ++i)
#pragma unroll
      for (int jj = 0; jj < 4; ++jj)
        acc[i][jj] = __builtin_amdgcn_mfma_f32_16x16x32_bf16(af[i], bfr[jj], acc[i][jj], 0, 0, 0);
    __builtin_amdgcn_s_barrier();        // all waves done reading buf
    __builtin_amdgcn_sched_barrier(0);   // keep re-stage below the barrier
    if (k0 + 64 < Kdim) GEMM_STAGE(k0 + 64, buf);  // overwrite safe now
    buf ^= 1;
  }

  if (MODE == 0) {
#pragma unroll
    for (int jj = 0; jj < 4; ++jj) {
      int col = colBase + wc * 64 + jj * 16 + j;
      int hh = col / 192;
      int rem = col - hh * 192;
      int mm = rem >> 6;   // wave-uniform (16-col runs never cross a 64 boundary)
      int dd = rem & 63;
      float hmv = hm[hh];
      float bv = bias[col];
      float sc = (mm == 0) ? hmv * 0.18033688011112042f : hmv;  // log2(e)/8 folded into Q
#pragma unroll
      for (int i = 0; i < 4; ++i) {
#pragma unroll
        for (int r = 0; r < 4; ++r) {
          int row = rowBase + wr * 64 + i * 16 + quad * 4 + r;
          int n = row >> 11, ss = row & 2047;
          size_t nh = (size_t)(n * 16 + hh);
          float val = (acc[i][jj][r] + bv) * sc;
          if (mm == 0) {
            Qp[nh * 131072 + ss * 64 + dd] = (bf16)val;
          } else if (mm == 1) {
            // lane-local-P Kf: g = ss&127, T = ss>>7,
            // ct = 2*((g>>5)&3) + ((g>>2)&1), i = ((g>>3)&3)*4 + (g&3)
            size_t idx = nh * 131072 + (size_t)(ss >> 7) * 8192 +
                         (size_t)(2 * ((ss >> 5) & 3) + ((ss >> 2) & 1)) * 1024 +
                         (dd >> 5) * 512 + ((dd >> 3) & 3) * 128 +
                         (((ss >> 3) & 3) * 4 + (ss & 3)) * 8 + (dd & 7);
            Kp[idx] = (bf16)val;
          } else {
            // natural fragment-major V: tile (ss>>7), block (kk=(ss>>5)&3, dt=dd>>4),
            // within block quad=(ss>>3)&3, j=dd&15, elem=ss&7
            size_t idx = nh * 131072 + (size_t)(ss >> 7) * 8192 +
                         (((ss >> 5) & 3) * 4 + (dd >> 4)) * 512 +
                         ((ss >> 3) & 3) * 128 + (dd & 15) * 8 + (ss & 7);
            Vp[idx] = (bf16)val;
          }
        }
      }
    }
  } else {
#pragma unroll
    for (int jj = 0; jj < 4; ++jj) {
      int col = colBase + wc * 64 + jj * 16 + j;
      float bv = bias[col];
#pragma unroll
      for (int i = 0; i < 4; ++i)
#pragma unroll
        for (int r = 0; r < 4; ++r) {
          int row = rowBase + wr * 64 + i * 16 + quad * 4 + r;
          outF[(size_t)row * Ncols + col] = acc[i][jj][r] + bv;
        }
    }
  }
}

// ---------------- Flash attention: 32-key subtiles, 4 blocks/CU ------------
// ROUND-14 CHANGE (one variable): staging subtile 64 -> 32 keys. Round-13
// counters (MfmaUtil 27 / VALU 50 / HBM 5 / occ 34) show flash wave-starved
// at 2 blocks/CU, limited solely by the 64KB K/V double-buffers. Both Kf and
// Vf are key-linear at 32-key (4KB) granularity (ct-pair {2s,2s+1} covers
// keys 32s..32s+31 contiguously; Vf kk-block likewise), so halving the
// subtile shrinks LDS to one 32KB pool (+1KB Lsh) -> 4 blocks/CU = 32
// waves/CU (2x). Per-subtile work halves (8 QK + 8 PV MFMA); lrow/oacc
// accumulation order is the SAME global ct/key sequence -> bit-identical
// output. The 32KB pool doubles as the Osh merge overlay (exactly 8192
// floats). keep __launch_bounds__(512,4) -- no tight VGPR cap (round-10
// lesson); round 13 fit in 64 VGPR with MORE live state (pkd 16->8 dwords).
// T5 setprio retained from round 12.
#define FLASH_STAGE(tileIdx, kOff, vOff)                                    \
  {                                                                         \
    const bf16* kn_ = Kc + (tileIdx) * 2048;                                \
    const bf16* vn_ = Vc + (tileIdx) * 2048;                                \
    int c = ts * 8;                                                         \
    async_ld16(kn_ + c, &KVpool[(kOff) + c]);                               \
    async_ld16(vn_ + c, &KVpool[(vOff) + c]);                               \
  }

#define FLASH_TILE(kOff, vOff)                                              \
  {                                                                         \
    unsigned pkd[2][2][2];                                                  \
    _Pragma("unroll")                                                       \
    for (int ct = 0; ct < 2; ++ct) {                                        \
      bf16x8 kf0 = *(const bf16x8*)&KVpool[(kOff) + ct * 1024 + lane * 8];  \
      bf16x8 kf1 = *(const bf16x8*)&KVpool[(kOff) + ct * 1024 + 512 + lane * 8]; \
      _Pragma("unroll")                                                     \
      for (int rt = 0; rt < 2; ++rt) {                                      \
        f32x4 sv = z4;                                                      \
        __builtin_amdgcn_s_setprio(1);                                      \
        sv = __builtin_amdgcn_mfma_f32_16x16x32_bf16(kf0, qf[rt][0], sv, 0, 0, 0); \
        sv = __builtin_amdgcn_mfma_f32_16x16x32_bf16(kf1, qf[rt][1], sv, 0, 0, 0); \
        __builtin_amdgcn_s_setprio(0);                                      \
        float p0 = EXP2F(sv[0]), p1 = EXP2F(sv[1]);                         \
        float p2 = EXP2F(sv[2]), p3 = EXP2F(sv[3]);                         \
        lrow[rt] += (p0 + p1) + (p2 + p3);                                  \
        pkd[rt][ct][0] = pack2(p0, p1);                                     \
        pkd[rt][ct][1] = pack2(p2, p3);                                     \
      }                                                                     \
    }                                                                       \
    __builtin_amdgcn_s_setprio(1);                                          \
    {                                                                       \
      union { uint4x u; bf16x8 h; } pa[2];                                  \
      _Pragma("unroll")                                                     \
      for (int rt = 0; rt < 2; ++rt)                                        \
        pa[rt].u = (uint4x){pkd[rt][0][0], pkd[rt][0][1],                   \
                            pkd[rt][1][0], pkd[rt][1][1]};                  \
      _Pragma("unroll")                                                     \
      for (int dt = 0; dt < 4; ++dt) {                                      \
        bf16x8 vf = *(const bf16x8*)&KVpool[(vOff) + dt * 512 + lane * 8];  \
        oacc[0][dt] = __builtin_amdgcn_mfma_f32_16x16x32_bf16(pa[0].h, vf, oacc[0][dt], 0, 0, 0); \
        oacc[1][dt] = __builtin_amdgcn_mfma_f32_16x16x32_bf16(pa[1].h, vf, oacc[1][dt], 0, 0, 0); \
      }                                                                     \
    }                                                                       \
    __builtin_amdgcn_s_setprio(0);                                          \
  }

__global__ __launch_bounds__(512, 4) void flash_kernel(const bf16* __restrict__ Qp,
                                                       const bf16* __restrict__ Kf,
                                                       const bf16* __restrict__ Vf,
                                                       bf16* __restrict__ attn) {
  __shared__ bf16 KVpool[16384];     // 32 KB: K bufs [0..8191], V bufs [8192..16383]
  __shared__ float Lsh[8][32];       // per-wave folded l  1 KB
  const int t = threadIdx.x, lane = t & 63, w = t >> 6;
  const int ts = t & 255;            // thread id within chunk-half
  const int hc = t >> 8;             // chunk (0: waves 0-3, 1: waves 4-7)
  const int j = lane & 15, quad = lane >> 4;
  const int b = blockIdx.x;
  const int qt = b >> 5;             // [0,16)
  const int nh = b & 31;
  const int q0 = qt * 128 + (w & 3) * 32;
  const bf16* Qb = Qp + (size_t)nh * 131072;
  const bf16* Kc = Kf + (size_t)nh * 131072 + hc * 65536;
  const bf16* Vc = Vf + (size_t)nh * 131072 + hc * 65536;

  // pool offsets: K buf b of chunk hc at (hc*2+b)*2048; V at 8192 + same
  const int kb0 = (hc * 2 + 0) * 2048, kb1 = (hc * 2 + 1) * 2048;
  const int vb0 = 8192 + kb0, vb1 = 8192 + kb1;

  bf16x8 qf[2][2];
#pragma unroll
  for (int rt = 0; rt < 2; ++rt)
#pragma unroll
    for (int kd = 0; kd < 2; ++kd)
      qf[rt][kd] = *(const bf16x8*)&Qb[(size_t)(q0 + rt * 16 + j) * 64 + kd * 32 + quad * 8];

  float lrow[2] = {0.f, 0.f};
  f32x4 oacc[2][4];
  const f32x4 z4 = {0.f, 0.f, 0.f, 0.f};
#pragma unroll
  for (int rt = 0; rt < 2; ++rt)
#pragma unroll
    for (int dt = 0; dt < 4; ++dt) oacc[rt][dt] = z4;

  // prologue: stage 32-key subtile 0 into buffer 0
  FLASH_STAGE(0, kb0, vb0);

  for (int it2 = 0; it2 < 16; ++it2) {
    __syncthreads();  // drains buf0 staging; all waves done reading buf1
    FLASH_STAGE(it2 * 2 + 1, kb1, vb1);   // overlaps compute below
    FLASH_TILE(kb0, vb0);
    __syncthreads();  // drains buf1 staging; all waves done reading buf0
    if (it2 < 15) FLASH_STAGE(it2 * 2 + 2, kb0, vb0);
    FLASH_TILE(kb1, vb1);
  }

  // ---- in-block chunk merge ----
  // fold l across quads: lane (0,j) holds l for q = q0 + rt*16 + j
  float lf[2];
#pragma unroll
  for (int rt = 0; rt < 2; ++rt) {
    float l = lrow[rt];
    l += __shfl_xor(l, 16);
    l += __shfl_xor(l, 32);
    lf[rt] = l;
  }
  __syncthreads();  // all waves done with KVpool -> safe to overlay Osh
  if (quad == 0) {
    Lsh[w][j] = lf[0];
    Lsh[w][16 + j] = lf[1];
  }
  float* Osh = (float*)&KVpool[0];  // 32 KB = 4 waves x 2rt x 4dt x 4r x 64
  if (w >= 4) {
    int wb = w - 4;
#pragma unroll
    for (int rt = 0; rt < 2; ++rt)
#pragma unroll
      for (int dt = 0; dt < 4; ++dt)
#pragma unroll
        for (int r = 0; r < 4; ++r)
          Osh[((((wb * 2 + rt) * 4 + dt) * 4) + r) * 64 + lane] = oacc[rt][dt][r];
  }
  __syncthreads();  // Osh + Lsh visible
  if (w < 4) {
    int n = nh >> 4, h = nh & 15;
    float inv[2][4];
#pragma unroll
    for (int rt = 0; rt < 2; ++rt)
#pragma unroll
      for (int r = 0; r < 4; ++r) {
        int idx = rt * 16 + quad * 4 + r;
        inv[rt][r] = 1.0f / (Lsh[w][idx] + Lsh[w + 4][idx]);
      }
#pragma unroll
    for (int rt = 0; rt < 2; ++rt)
#pragma unroll
      for (int r = 0; r < 4; ++r) {
        int s = q0 + rt * 16 + quad * 4 + r;
        size_t base = ((size_t)(n * 2048 + s)) * 1024 + h * 64;
#pragma unroll
        for (int dt = 0; dt < 4; ++dt) {
          float o = oacc[rt][dt][r] +
                    Osh[((((w * 2 + rt) * 4 + dt) * 4) + r) * 64 + lane];
          attn[base + dt * 16 + j] = (bf16)(o * inv[rt][r]);
        }
      }
  }
}

extern "C" void kernel_launch(void* const* d_in, const int* in_sizes, int n_in,
                              void* d_out, int out_size, void* d_ws, size_t ws_size,
                              hipStream_t stream) {
  const float* x = (const float*)d_in[0];
  const float* head_mask = (const float*)d_in[1];
  const float* qkv_w = (const float*)d_in[2];
  const float* qkv_b = (const float*)d_in[3];
  const float* fc_w = (const float*)d_in[4];
  const float* fc_b = (const float*)d_in[5];
  float* out = (float*)d_out;

  char* ws = (char*)d_ws;
  bf16* x_bf    = (bf16*)(ws + 0);                    // 8 MB (later reused as attn)
  bf16* qkvw_bf = (bf16*)(ws + ((size_t)8 << 20));    // 6 MB
  bf16* fcw_bf  = (bf16*)(ws + ((size_t)14 << 20));   // 2 MB
  bf16* Qp      = (bf16*)(ws + ((size_t)16 << 20));   // 8 MB
  bf16* Kf      = (bf16*)(ws + ((size_t)24 << 20));   // 8 MB (fragment-major K, lane-local-P perm)
  bf16* Vf      = (bf16*)(ws + ((size_t)32 << 20));   // 8 MB (fragment-major V, natural order)
  bf16* attn = x_bf;              // x_bf dead after gemm1

  cvt3_kernel<<<8192, 256, 0, stream>>>(x, qkv_w, fc_w, x_bf, qkvw_bf, fcw_bf);
  gemm_bt_kernel<0><<<32 * 24, 256, 0, stream>>>(x_bf, qkvw_bf, qkv_b, head_mask,
                                                 Qp, Kf, Vf, nullptr, 3072, 1024, 32);
  flash_kernel<<<512, 512, 0, stream>>>(Qp, Kf, Vf, attn);
  gemm_bt_kernel<1><<<32 * 8, 256, 0, stream>>>(attn, fcw_bf, fc_b, nullptr,
                                                nullptr, nullptr, nullptr, out, 1024, 1024, 32);
}